// Round 2
// baseline (673.127 us; speedup 1.0000x reference)
//
#include <hip/hip_runtime.h>
#include <hip/hip_bf16.h>

// ---------- helpers ----------
typedef short short8 __attribute__((ext_vector_type(8)));
typedef float f32x4 __attribute__((ext_vector_type(4)));

__device__ inline unsigned short f2bf(float x) {
  union { float f; unsigned u; } un; un.f = x;
  unsigned r = un.u + 0x7FFFu + ((un.u >> 16) & 1u);
  return (unsigned short)(r >> 16);
}
__device__ inline float bf2f(unsigned short u) {
  union { unsigned u; float f; } un; un.u = ((unsigned)u) << 16; return un.f;
}

// ---------- weight prep: WcatT [768][128] bf16 (row n = output col), WgTopT [128][128], bcat[768] ----------
__global__ void prep_weights(const float* __restrict__ Wq, const float* __restrict__ bq,
                             const float* __restrict__ Wk, const float* __restrict__ bk,
                             const float* __restrict__ Wv, const float* __restrict__ bv,
                             const float* __restrict__ Ws, const float* __restrict__ bs,
                             const float* __restrict__ Wsp, const float* __restrict__ bsp,
                             const float* __restrict__ Wg, const float* __restrict__ bg,
                             unsigned short* __restrict__ WcatT, unsigned short* __restrict__ WgTopT,
                             float* __restrict__ bcat) {
  int tid = blockIdx.x * 256 + threadIdx.x;
  if (tid >= 768 * 128) return;
  int n = tid >> 7, k = tid & 127;
  int s = n >> 7, c = n & 127;
  float val;
  if (s == 0) val = Wq[k * 128 + c];
  else if (s == 1) val = Wk[k * 128 + c];
  else if (s == 2) val = Wv[k * 128 + c];
  else if (s == 3) val = Ws[k * 128 + c];
  else if (s == 4) val = Wsp[k * 128 + c];
  else val = Wg[(128 + k) * 128 + c];   // bottom half of Wg (x part of concat)
  WcatT[tid] = f2bf(val);
  if (n < 128) WgTopT[n * 128 + k] = f2bf(Wg[k * 128 + n]);  // top half of Wg, transposed
  if (k == 0) {
    float bv2;
    if (s == 0) bv2 = bq[c]; else if (s == 1) bv2 = bk[c]; else if (s == 2) bv2 = bv[c];
    else if (s == 3) bv2 = bs[c]; else if (s == 4) bv2 = bsp[c]; else bv2 = bg[c];
    bcat[n] = bv2;
  }
}

__global__ void convert_bf16(const float* __restrict__ x, unsigned short* __restrict__ xb, int n4) {
  int i = blockIdx.x * 256 + threadIdx.x;
  if (i < n4) {
    float4 v = ((const float4*)x)[i];
    ushort4 o;
    o.x = f2bf(v.x); o.y = f2bf(v.y); o.z = f2bf(v.z); o.w = f2bf(v.w);
    ((ushort4*)xb)[i] = o;
  }
}

// ---------- CSR build ----------
__global__ void count_deg(const int* __restrict__ dst, int* __restrict__ deg, int E) {
  int i = blockIdx.x * 256 + threadIdx.x;
  if (i < E) atomicAdd(&deg[dst[i]], 1);
}

__global__ __launch_bounds__(1024) void scan_kernel(const int* __restrict__ deg, int* __restrict__ off,
                                                    int* __restrict__ cursor, int n) {
  __shared__ int part[1024];
  int t = threadIdx.x;
  int CH = (n + 1023) / 1024;
  int base = t * CH;
  int s = 0;
  for (int j = 0; j < CH; ++j) { int i = base + j; if (i < n) s += deg[i]; }
  part[t] = s;
  __syncthreads();
  for (int d = 1; d < 1024; d <<= 1) {
    int v = (t >= d) ? part[t - d] : 0;
    __syncthreads();
    part[t] += v;
    __syncthreads();
  }
  int ex = (t == 0) ? 0 : part[t - 1];
  for (int j = 0; j < CH; ++j) {
    int i = base + j;
    if (i < n) { off[i] = ex; cursor[i] = ex; ex += deg[i]; }
  }
  if (t == 1023) off[n] = part[1023];
}

// store (eid, src) packed so the hot loop has no indirection
__global__ void scatter_kernel(const int* __restrict__ ei, int* __restrict__ cursor,
                               int2* __restrict__ slotsrc, int E) {
  int i = blockIdx.x * 256 + threadIdx.x;
  if (i < E) {
    int s = ei[i];
    int d = ei[E + i];
    int p = atomicAdd(&cursor[d], 1);
    slotsrc[p] = make_int2(i, s);
  }
}

// ---------- bf16 MFMA GEMM: C[M,slice] = A[M,128] @ BT[Nout,128]^T (+bias) ----------
// For blockIdx.y==1/2 (k/v segments) the result is written as packed bf16 into the
// (unused-f32) byte range of Y's k/v columns: (ushort*)(C + row*768 + 128) + (col-128).
__global__ __launch_bounds__(256) void gemm_k128(const unsigned short* __restrict__ A,
                                                 const unsigned short* __restrict__ BT,
                                                 const float* __restrict__ bias,
                                                 float* __restrict__ C, int M, int ldc,
                                                 int kv_bf16) {
  __shared__ char As[32768];
  __shared__ char Bs[32768];
  int m0 = blockIdx.x * 128;
  int n0 = blockIdx.y * 128;
  int t = threadIdx.x;
  {
    int row = t >> 1;
    int hb = (t & 1) * 128;
    const char* srow = (const char*)(A + (size_t)(m0 + row) * 128);
    bool ok = (m0 + row) < M;
    char* lrow = As + row * 256;
    int sw = (row & 7) << 4;
#pragma unroll
    for (int j = 0; j < 8; ++j) {
      int b = hb + j * 16;
      uint4 val;
      if (ok) val = *(const uint4*)(srow + b);
      else { val.x = 0; val.y = 0; val.z = 0; val.w = 0; }
      *(uint4*)(lrow + (b ^ sw)) = val;
    }
  }
  {
    int row = t >> 1;
    int hb = (t & 1) * 128;
    const char* srow = (const char*)(BT + (size_t)(n0 + row) * 128);
    char* lrow = Bs + row * 256;
    int sw = (row & 7) << 4;
#pragma unroll
    for (int j = 0; j < 8; ++j) {
      int b = hb + j * 16;
      uint4 val = *(const uint4*)(srow + b);
      *(uint4*)(lrow + (b ^ sw)) = val;
    }
  }
  __syncthreads();
  int w = t >> 6, lane = t & 63;
  int lm = lane & 15, hi = lane >> 4;
  f32x4 acc[2][8] = {};
#pragma unroll
  for (int kb = 0; kb < 4; ++kb) {
    int colb = kb * 64 + hi * 16;
    short8 a[2];
#pragma unroll
    for (int rf = 0; rf < 2; ++rf) {
      int row = w * 32 + rf * 16 + lm;
      a[rf] = *(const short8*)(As + row * 256 + (colb ^ ((row & 7) << 4)));
    }
#pragma unroll
    for (int cf = 0; cf < 8; ++cf) {
      int row = cf * 16 + lm;
      short8 b = *(const short8*)(Bs + row * 256 + (colb ^ ((row & 7) << 4)));
      acc[0][cf] = __builtin_amdgcn_mfma_f32_16x16x32_bf16(a[0], b, acc[0][cf], 0, 0, 0);
      acc[1][cf] = __builtin_amdgcn_mfma_f32_16x16x32_bf16(a[1], b, acc[1][cf], 0, 0, 0);
    }
  }
  bool to16 = kv_bf16 && (blockIdx.y == 1 || blockIdx.y == 2);
#pragma unroll
  for (int rf = 0; rf < 2; ++rf) {
#pragma unroll
    for (int cf = 0; cf < 8; ++cf) {
      int col = n0 + cf * 16 + lm;
      float bv = bias ? bias[col] : 0.0f;
#pragma unroll
      for (int j = 0; j < 4; ++j) {
        int row = m0 + w * 32 + rf * 16 + hi * 4 + j;
        if (row < M) {
          float val = acc[rf][cf][j] + bv;
          if (to16) {
            unsigned short* kvrow = (unsigned short*)(C + (size_t)row * 768 + 128);
            kvrow[col - 128] = f2bf(val);
          } else {
            C[(size_t)row * ldc + col] = val;
          }
        }
      }
    }
  }
}

// ---------- node-centric online-softmax edge aggregation (pipelined) ----------
// Y: [N,768]; q f32 at +0, packed bf16 k|v at byte offset 512 of each row, xs/skip/gx f32.
// One wave = (node, half). ch = half*64 + lane.
__global__ __launch_bounds__(256) void edge_aggregate(const int2* __restrict__ slotsrc,
                                                      const int* __restrict__ off,
                                                      const float* __restrict__ edge_attr,
                                                      const float* __restrict__ We,
                                                      const float* __restrict__ Y,
                                                      float* __restrict__ agg, int Nn) {
  int w = threadIdx.x >> 6, lane = threadIdx.x & 63;
  int node = blockIdx.x * 2 + (w >> 1);
  if (node >= Nn) return;
  int half = w & 1;
  int ch = half * 64 + lane;
  float we[16];
#pragma unroll
  for (int t2 = 0; t2 < 16; ++t2) we[t2] = We[t2 * 128 + ch];
  // fold 1/sqrt(32) * log2(e) into q so alpha lives in log2 domain
  float q_l = Y[(size_t)node * 768 + ch] * 0.25505654f;
  float m = -INFINITY, den = 0.0f, acc = 0.0f;
  int beg = off[node], end = off[node + 1];

  int eidA = 0, srcA = 0, eidB = 0, srcB = 0;
  float4 aA0, aA1, aA2, aA3;
  unsigned short kA = 0, vA = 0;
  if (beg < end) {
    int2 s0 = slotsrc[beg];
    eidA = __builtin_amdgcn_readfirstlane(s0.x);
    srcA = __builtin_amdgcn_readfirstlane(s0.y);
    const float4* ar = (const float4*)edge_attr + (size_t)eidA * 4;
    aA0 = ar[0]; aA1 = ar[1]; aA2 = ar[2]; aA3 = ar[3];
    const unsigned short* kv = (const unsigned short*)(Y + (size_t)srcA * 768 + 128);
    kA = kv[ch]; vA = kv[128 + ch];
  }
  if (beg + 1 < end) {
    int2 s1 = slotsrc[beg + 1];
    eidB = __builtin_amdgcn_readfirstlane(s1.x);
    srcB = __builtin_amdgcn_readfirstlane(s1.y);
  }
  for (int p = beg; p < end; ++p) {
    float4 c0 = aA0, c1 = aA1, c2 = aA2, c3 = aA3;
    unsigned short ck = kA, cv = vA;
    // prefetch attr/kv for edge p+1 (indices already resident), indices for p+2
    if (p + 1 < end) {
      const float4* ar = (const float4*)edge_attr + (size_t)eidB * 4;
      aA0 = ar[0]; aA1 = ar[1]; aA2 = ar[2]; aA3 = ar[3];
      const unsigned short* kv = (const unsigned short*)(Y + (size_t)srcB * 768 + 128);
      kA = kv[ch]; vA = kv[128 + ch];
    }
    if (p + 2 < end) {
      int2 s2 = slotsrc[p + 2];
      eidB = __builtin_amdgcn_readfirstlane(s2.x);
      srcB = __builtin_amdgcn_readfirstlane(s2.y);
    }
    float e_l = c0.x * we[0];
    e_l = fmaf(c0.y, we[1], e_l);  e_l = fmaf(c0.z, we[2], e_l);  e_l = fmaf(c0.w, we[3], e_l);
    e_l = fmaf(c1.x, we[4], e_l);  e_l = fmaf(c1.y, we[5], e_l);  e_l = fmaf(c1.z, we[6], e_l);
    e_l = fmaf(c1.w, we[7], e_l);  e_l = fmaf(c2.x, we[8], e_l);  e_l = fmaf(c2.y, we[9], e_l);
    e_l = fmaf(c2.z, we[10], e_l); e_l = fmaf(c2.w, we[11], e_l); e_l = fmaf(c3.x, we[12], e_l);
    e_l = fmaf(c3.y, we[13], e_l); e_l = fmaf(c3.z, we[14], e_l); e_l = fmaf(c3.w, we[15], e_l);
    float kf = bf2f(ck) + e_l;
    float prod = q_l * kf;
#pragma unroll
    for (int o = 16; o; o >>= 1) prod += __shfl_xor(prod, o, 32);
    float alpha = prod;                       // log2 domain
    float mn = fmaxf(m, alpha);
    float sc = exp2f(m - mn);
    float pt = exp2f(alpha - mn);
    float vf = bf2f(cv) + e_l;
    den = den * sc + pt;
    acc = acc * sc + pt * vf;
    m = mn;
  }
  agg[(size_t)node * 128 + ch] = acc / (den + 1e-16f);
}

// ---------- LN1 + GELU ----------
__global__ __launch_bounds__(256) void ln_gelu_kernel(const float* __restrict__ agg,
                                                      const float* __restrict__ Y,
                                                      const float* __restrict__ g1,
                                                      const float* __restrict__ b1,
                                                      float* __restrict__ u,
                                                      unsigned short* __restrict__ ub, int Nn) {
  int w = threadIdx.x >> 6, lane = threadIdx.x & 63;
  int row = blockIdx.x * 4 + w;
  if (row >= Nn) return;
  const float* yrow = Y + (size_t)row * 768 + 384;  // xs segment
  const float* arow = agg + (size_t)row * 128;
  float h0 = arow[lane] + yrow[lane];
  float h1 = arow[lane + 64] + yrow[lane + 64];
  float s = h0 + h1;
#pragma unroll
  for (int o = 32; o; o >>= 1) s += __shfl_xor(s, o, 64);
  float mean = s * (1.0f / 128.0f);
  float d0 = h0 - mean, d1 = h1 - mean;
  float ss = d0 * d0 + d1 * d1;
#pragma unroll
  for (int o = 32; o; o >>= 1) ss += __shfl_xor(ss, o, 64);
  float rs = rsqrtf(ss * (1.0f / 128.0f) + 1e-5f);
  float y0 = d0 * rs * g1[lane] + b1[lane];
  float y1 = d1 * rs * g1[lane + 64] + b1[lane + 64];
  float u0 = 0.5f * y0 * (1.0f + erff(y0 * 0.7071067811865475f));
  float u1 = 0.5f * y1 * (1.0f + erff(y1 * 0.7071067811865475f));
  size_t base = (size_t)row * 128;
  u[base + lane] = u0;
  u[base + lane + 64] = u1;
  ub[base + lane] = f2bf(u0);
  ub[base + lane + 64] = f2bf(u1);
}

// ---------- gate + LN2 -> out ----------
__global__ __launch_bounds__(256) void gate_ln_kernel(const float* __restrict__ gate_u,
                                                      const float* __restrict__ Y,
                                                      const float* __restrict__ u,
                                                      const float* __restrict__ g2,
                                                      const float* __restrict__ b2,
                                                      float* __restrict__ out, int Nn) {
  int w = threadIdx.x >> 6, lane = threadIdx.x & 63;
  int row = blockIdx.x * 4 + w;
  if (row >= Nn) return;
  const float* yrow = Y + (size_t)row * 768;
  size_t base = (size_t)row * 128;
  float z0 = gate_u[base + lane] + yrow[640 + lane];            // gate_x (has bg)
  float z1 = gate_u[base + lane + 64] + yrow[640 + lane + 64];
  float gg0 = 1.0f / (1.0f + __expf(-z0));
  float gg1 = 1.0f / (1.0f + __expf(-z1));
  float u0 = u[base + lane], u1 = u[base + lane + 64];
  float s0 = yrow[512 + lane], s1 = yrow[512 + lane + 64];      // skip
  float h0 = gg0 * u0 + (1.0f - gg0) * s0;
  float h1 = gg1 * u1 + (1.0f - gg1) * s1;
  float s = h0 + h1;
#pragma unroll
  for (int o = 32; o; o >>= 1) s += __shfl_xor(s, o, 64);
  float mean = s * (1.0f / 128.0f);
  float d0 = h0 - mean, d1 = h1 - mean;
  float ss = d0 * d0 + d1 * d1;
#pragma unroll
  for (int o = 32; o; o >>= 1) ss += __shfl_xor(ss, o, 64);
  float rs = rsqrtf(ss * (1.0f / 128.0f) + 1e-5f);
  out[base + lane] = d0 * rs * g2[lane] + b2[lane];
  out[base + lane + 64] = d1 * rs * g2[lane + 64] + b2[lane + 64];
}

// ---------- launch ----------
extern "C" void kernel_launch(void* const* d_in, const int* in_sizes, int n_in,
                              void* d_out, int out_size, void* d_ws, size_t ws_size,
                              hipStream_t stream) {
  const float* x = (const float*)d_in[0];
  const int* edge_index = (const int*)d_in[1];
  const float* edge_attr = (const float*)d_in[2];
  const float* Wq = (const float*)d_in[3];
  const float* bq = (const float*)d_in[4];
  const float* Wk = (const float*)d_in[5];
  const float* bk = (const float*)d_in[6];
  const float* Wv = (const float*)d_in[7];
  const float* bv = (const float*)d_in[8];
  const float* We = (const float*)d_in[9];
  const float* Ws = (const float*)d_in[10];
  const float* bs = (const float*)d_in[11];
  const float* Wsp = (const float*)d_in[12];
  const float* bsp = (const float*)d_in[13];
  const float* Wg = (const float*)d_in[14];
  const float* bg = (const float*)d_in[15];
  const float* g1 = (const float*)d_in[16];
  const float* b1 = (const float*)d_in[17];
  const float* g2 = (const float*)d_in[18];
  const float* b2 = (const float*)d_in[19];

  int Nn = in_sizes[0] / 128;
  int E = in_sizes[1] / 2;

  char* p = (char*)d_ws;
  auto alloc = [&](size_t bytes) -> char* {
    char* r = p;
    p += (bytes + 255) & ~(size_t)255;
    return r;
  };
  float* Y = (float*)alloc((size_t)Nn * 768 * 4);       // q | bf16 kv | xs | skip | gate_x
  float* agg = (float*)alloc((size_t)Nn * 128 * 4);
  float* u = (float*)alloc((size_t)Nn * 128 * 4);
  float* gate_u = (float*)alloc((size_t)Nn * 128 * 4);
  unsigned short* xb = (unsigned short*)alloc((size_t)Nn * 128 * 2);
  unsigned short* ub = (unsigned short*)alloc((size_t)Nn * 128 * 2);
  unsigned short* WcatT = (unsigned short*)alloc(768 * 128 * 2);
  unsigned short* WgTopT = (unsigned short*)alloc(128 * 128 * 2);
  float* bcat = (float*)alloc(768 * 4);
  int* deg = (int*)alloc((size_t)Nn * 4);
  int* off = (int*)alloc((size_t)(Nn + 1) * 4);
  int* cursor = (int*)alloc((size_t)Nn * 4);
  int2* slotsrc = (int2*)alloc((size_t)E * 8);

  hipMemsetAsync(deg, 0, (size_t)Nn * 4, stream);
  prep_weights<<<(768 * 128 + 255) / 256, 256, 0, stream>>>(Wq, bq, Wk, bk, Wv, bv, Ws, bs,
                                                            Wsp, bsp, Wg, bg, WcatT, WgTopT, bcat);
  convert_bf16<<<((Nn * 128 / 4) + 255) / 256, 256, 0, stream>>>(x, xb, Nn * 128 / 4);
  count_deg<<<(E + 255) / 256, 256, 0, stream>>>(edge_index + E, deg, E);
  scan_kernel<<<1, 1024, 0, stream>>>(deg, off, cursor, Nn);
  scatter_kernel<<<(E + 255) / 256, 256, 0, stream>>>(edge_index, cursor, slotsrc, E);

  dim3 g1g((Nn + 127) / 128, 6);
  gemm_k128<<<g1g, 256, 0, stream>>>(xb, WcatT, bcat, Y, Nn, 768, 1);

  edge_aggregate<<<(Nn + 1) / 2, 256, 0, stream>>>(slotsrc, off, edge_attr, We, Y, agg, Nn);

  ln_gelu_kernel<<<(Nn + 3) / 4, 256, 0, stream>>>(agg, Y, g1, b1, u, ub, Nn);

  dim3 g2g((Nn + 127) / 128, 1);
  gemm_k128<<<g2g, 256, 0, stream>>>(ub, WgTopT, nullptr, gate_u, Nn, 128, 0);

  gate_ln_kernel<<<(Nn + 3) / 4, 256, 0, stream>>>(gate_u, Y, u, g2, b2, (float*)d_out, Nn);
}

// Round 4
// 457.951 us; speedup vs baseline: 1.4699x; 1.4699x over previous
//
#include <hip/hip_runtime.h>
#include <hip/hip_bf16.h>

// ---------- helpers ----------
typedef short short8 __attribute__((ext_vector_type(8)));
typedef float f32x4 __attribute__((ext_vector_type(4)));

__device__ inline unsigned short f2bf(float x) {
  union { float f; unsigned u; } un; un.f = x;
  unsigned r = un.u + 0x7FFFu + ((un.u >> 16) & 1u);
  return (unsigned short)(r >> 16);
}
__device__ inline float bf2f(unsigned short u) {
  union { unsigned u; float f; } un; un.u = ((unsigned)u) << 16; return un.f;
}

// ---------- weight prep: WcatT [768][128] bf16 (row n = output col), WgTopT [128][128], bcat[768] ----------
__global__ void prep_weights(const float* __restrict__ Wq, const float* __restrict__ bq,
                             const float* __restrict__ Wk, const float* __restrict__ bk,
                             const float* __restrict__ Wv, const float* __restrict__ bv,
                             const float* __restrict__ Ws, const float* __restrict__ bs,
                             const float* __restrict__ Wsp, const float* __restrict__ bsp,
                             const float* __restrict__ Wg, const float* __restrict__ bg,
                             unsigned short* __restrict__ WcatT, unsigned short* __restrict__ WgTopT,
                             float* __restrict__ bcat) {
  int tid = blockIdx.x * 256 + threadIdx.x;
  if (tid >= 768 * 128) return;
  int n = tid >> 7, k = tid & 127;
  int s = n >> 7, c = n & 127;
  float val;
  if (s == 0) val = Wq[k * 128 + c];
  else if (s == 1) val = Wk[k * 128 + c];
  else if (s == 2) val = Wv[k * 128 + c];
  else if (s == 3) val = Ws[k * 128 + c];
  else if (s == 4) val = Wsp[k * 128 + c];
  else val = Wg[(128 + k) * 128 + c];   // bottom half of Wg (x part of concat)
  WcatT[tid] = f2bf(val);
  if (n < 128) WgTopT[n * 128 + k] = f2bf(Wg[k * 128 + n]);  // top half of Wg, transposed
  if (k == 0) {
    float bv2;
    if (s == 0) bv2 = bq[c]; else if (s == 1) bv2 = bk[c]; else if (s == 2) bv2 = bv[c];
    else if (s == 3) bv2 = bs[c]; else if (s == 4) bv2 = bsp[c]; else bv2 = bg[c];
    bcat[n] = bv2;
  }
}

// ---------- We MFMA A-fragment table: wf[(b*64+lane)*8+j] = We[t][b*16+(lane&15)], t=(lane>>4)*8+j (<16) ----------
__global__ void prep_wefrag(const float* __restrict__ We, unsigned short* __restrict__ wf) {
  int id = blockIdx.x * 256 + threadIdx.x;
  if (id >= 4096) return;
  int j = id & 7, lane = (id >> 3) & 63, b = id >> 9;
  int t = (lane >> 4) * 8 + j;
  float v = (t < 16) ? We[t * 128 + b * 16 + (lane & 15)] : 0.0f;
  wf[id] = f2bf(v);
}

__global__ void convert_bf16(const float* __restrict__ x, unsigned short* __restrict__ xb, int n4) {
  int i = blockIdx.x * 256 + threadIdx.x;
  if (i < n4) {
    float4 v = ((const float4*)x)[i];
    ushort4 o;
    o.x = f2bf(v.x); o.y = f2bf(v.y); o.z = f2bf(v.z); o.w = f2bf(v.w);
    ((ushort4*)xb)[i] = o;
  }
}

// ---------- CSR build ----------
__global__ void count_deg(const int* __restrict__ dst, int* __restrict__ deg, int E) {
  int i = blockIdx.x * 256 + threadIdx.x;
  if (i < E) atomicAdd(&deg[dst[i]], 1);
}

__global__ __launch_bounds__(256) void scan_bsum(const int* __restrict__ deg, int* __restrict__ bsum, int n) {
  __shared__ int red[256];
  int b = blockIdx.x, t = threadIdx.x;
  int base = b * 1024 + t * 4;
  int s = 0;
#pragma unroll
  for (int j = 0; j < 4; ++j) { int i = base + j; if (i < n) s += deg[i]; }
  red[t] = s; __syncthreads();
  for (int o = 128; o; o >>= 1) { if (t < o) red[t] += red[t + o]; __syncthreads(); }
  if (t == 0) bsum[b] = red[0];
}

__global__ void scan_top(int* __restrict__ bsum, int G) {  // 64 threads, G<=64
  int lane = threadIdx.x;
  int v = (lane < G) ? bsum[lane] : 0;
  int orig = v;
#pragma unroll
  for (int d = 1; d < 64; d <<= 1) { int u = __shfl_up(v, d); if (lane >= d) v += u; }
  if (lane < G) bsum[lane] = v - orig;   // exclusive block base
}

__global__ __launch_bounds__(256) void scan_write(const int* __restrict__ deg, const int* __restrict__ bsum,
                                                  int* __restrict__ off, int* __restrict__ cursor, int n) {
  __shared__ int red[256];
  int b = blockIdx.x, t = threadIdx.x;
  int base = b * 1024 + t * 4;
  int d0 = 0, d1 = 0, d2 = 0, d3 = 0;
  if (base + 3 < n) {
    int4 d4 = *(const int4*)(deg + base);
    d0 = d4.x; d1 = d4.y; d2 = d4.z; d3 = d4.w;
  } else {
    if (base + 0 < n) d0 = deg[base + 0];
    if (base + 1 < n) d1 = deg[base + 1];
    if (base + 2 < n) d2 = deg[base + 2];
    if (base + 3 < n) d3 = deg[base + 3];
  }
  int tsum = d0 + d1 + d2 + d3;
  red[t] = tsum; __syncthreads();
  for (int o = 1; o < 256; o <<= 1) {
    int val = (t >= o) ? red[t - o] : 0;
    __syncthreads();
    red[t] += val;
    __syncthreads();
  }
  int run = bsum[b] + red[t] - tsum;
  if (base + 0 < n) { off[base + 0] = run; cursor[base + 0] = run; run += d0; }
  if (base + 1 < n) { off[base + 1] = run; cursor[base + 1] = run; run += d1; }
  if (base + 2 < n) { off[base + 2] = run; cursor[base + 2] = run; run += d2; }
  if (base + 3 < n) { off[base + 3] = run; cursor[base + 3] = run; run += d3; }
  if (b == gridDim.x - 1 && t == 255) off[n] = run;
}

// store (eid, src) packed so the hot loop has no indirection
__global__ void scatter_kernel(const int* __restrict__ ei, int* __restrict__ cursor,
                               int2* __restrict__ slotsrc, int E) {
  int i = blockIdx.x * 256 + threadIdx.x;
  if (i < E) {
    int s = ei[i];
    int d = ei[E + i];
    int p = atomicAdd(&cursor[d], 1);
    slotsrc[p] = make_int2(i, s);
  }
}

// ---------- fused 6-block GEMM: Y[M,768] = xb[M,128] @ WcatT^T + bcat ----------
// nb==1,2 (k/v segments) written as packed bf16 into bytes 512..1023 of each Y row.
__global__ __launch_bounds__(256) void gemm_fused(const unsigned short* __restrict__ A,
                                                  const unsigned short* __restrict__ BT,
                                                  const float* __restrict__ bias,
                                                  float* __restrict__ Y, int M) {
  __shared__ char As[32768];
  __shared__ char Bs[32768];
  int m0 = blockIdx.x * 128;
  int t = threadIdx.x;
  {
    int row = t >> 1;
    int hb = (t & 1) * 128;
    const char* srow = (const char*)(A + (size_t)(m0 + row) * 128);
    bool ok = (m0 + row) < M;
    char* lrow = As + row * 256;
    int sw = (row & 7) << 4;
#pragma unroll
    for (int j = 0; j < 8; ++j) {
      int b = hb + j * 16;
      uint4 val;
      if (ok) val = *(const uint4*)(srow + b);
      else { val.x = 0; val.y = 0; val.z = 0; val.w = 0; }
      *(uint4*)(lrow + (b ^ sw)) = val;
    }
  }
  int w = t >> 6, lane = t & 63;
  int lm = lane & 15, hi = lane >> 4;
  for (int nb = 0; nb < 6; ++nb) {
    __syncthreads();
    {
      int row = t >> 1;
      int hb = (t & 1) * 128;
      const char* srow = (const char*)(BT + (size_t)(nb * 128 + row) * 128);
      char* lrow = Bs + row * 256;
      int sw = (row & 7) << 4;
#pragma unroll
      for (int j = 0; j < 8; ++j) {
        int b = hb + j * 16;
        uint4 val = *(const uint4*)(srow + b);
        *(uint4*)(lrow + (b ^ sw)) = val;
      }
    }
    __syncthreads();
    f32x4 acc[2][8] = {};
#pragma unroll
    for (int kb = 0; kb < 4; ++kb) {
      int colb = kb * 64 + hi * 16;
      short8 a[2];
#pragma unroll
      for (int rf = 0; rf < 2; ++rf) {
        int row = w * 32 + rf * 16 + lm;
        a[rf] = *(const short8*)(As + row * 256 + (colb ^ ((row & 7) << 4)));
      }
#pragma unroll
      for (int cf = 0; cf < 8; ++cf) {
        int row = cf * 16 + lm;
        short8 bfr = *(const short8*)(Bs + row * 256 + (colb ^ ((row & 7) << 4)));
        acc[0][cf] = __builtin_amdgcn_mfma_f32_16x16x32_bf16(a[0], bfr, acc[0][cf], 0, 0, 0);
        acc[1][cf] = __builtin_amdgcn_mfma_f32_16x16x32_bf16(a[1], bfr, acc[1][cf], 0, 0, 0);
      }
    }
    bool to16 = (nb == 1 || nb == 2);
#pragma unroll
    for (int rf = 0; rf < 2; ++rf) {
#pragma unroll
      for (int cf = 0; cf < 8; ++cf) {
        int col = nb * 128 + cf * 16 + lm;
        float bv = bias[col];
#pragma unroll
        for (int j = 0; j < 4; ++j) {
          int row = m0 + w * 32 + rf * 16 + hi * 4 + j;
          if (row < M) {
            float val = acc[rf][cf][j] + bv;
            if (to16) {
              unsigned short* kvrow = (unsigned short*)((char*)Y + (size_t)row * 3072 + 512);
              kvrow[col - 128] = f2bf(val);
            } else {
              Y[(size_t)row * 768 + col] = val;
            }
          }
        }
      }
    }
  }
}

// ---------- plain 128-col GEMM (for gate top): C[M,128] = A[M,128] @ BT^T ----------
__global__ __launch_bounds__(256) void gemm_single(const unsigned short* __restrict__ A,
                                                   const unsigned short* __restrict__ BT,
                                                   float* __restrict__ C, int M) {
  __shared__ char As[32768];
  __shared__ char Bs[32768];
  int m0 = blockIdx.x * 128;
  int t = threadIdx.x;
  {
    int row = t >> 1;
    int hb = (t & 1) * 128;
    const char* srow = (const char*)(A + (size_t)(m0 + row) * 128);
    bool ok = (m0 + row) < M;
    char* lrow = As + row * 256;
    int sw = (row & 7) << 4;
#pragma unroll
    for (int j = 0; j < 8; ++j) {
      int b = hb + j * 16;
      uint4 val;
      if (ok) val = *(const uint4*)(srow + b);
      else { val.x = 0; val.y = 0; val.z = 0; val.w = 0; }
      *(uint4*)(lrow + (b ^ sw)) = val;
    }
  }
  {
    int row = t >> 1;
    int hb = (t & 1) * 128;
    const char* srow = (const char*)(BT + (size_t)row * 128);
    char* lrow = Bs + row * 256;
    int sw = (row & 7) << 4;
#pragma unroll
    for (int j = 0; j < 8; ++j) {
      int b = hb + j * 16;
      uint4 val = *(const uint4*)(srow + b);
      *(uint4*)(lrow + (b ^ sw)) = val;
    }
  }
  __syncthreads();
  int w = t >> 6, lane = t & 63;
  int lm = lane & 15, hi = lane >> 4;
  f32x4 acc[2][8] = {};
#pragma unroll
  for (int kb = 0; kb < 4; ++kb) {
    int colb = kb * 64 + hi * 16;
    short8 a[2];
#pragma unroll
    for (int rf = 0; rf < 2; ++rf) {
      int row = w * 32 + rf * 16 + lm;
      a[rf] = *(const short8*)(As + row * 256 + (colb ^ ((row & 7) << 4)));
    }
#pragma unroll
    for (int cf = 0; cf < 8; ++cf) {
      int row = cf * 16 + lm;
      short8 bfr = *(const short8*)(Bs + row * 256 + (colb ^ ((row & 7) << 4)));
      acc[0][cf] = __builtin_amdgcn_mfma_f32_16x16x32_bf16(a[0], bfr, acc[0][cf], 0, 0, 0);
      acc[1][cf] = __builtin_amdgcn_mfma_f32_16x16x32_bf16(a[1], bfr, acc[1][cf], 0, 0, 0);
    }
  }
#pragma unroll
  for (int rf = 0; rf < 2; ++rf) {
#pragma unroll
    for (int cf = 0; cf < 8; ++cf) {
      int col = cf * 16 + lm;
#pragma unroll
      for (int j = 0; j < 4; ++j) {
        int row = m0 + w * 32 + rf * 16 + hi * 4 + j;
        if (row < M) C[(size_t)row * 128 + col] = acc[rf][cf][j];
      }
    }
  }
}

// ---------- node-centric flash edge aggregation: 1 wave per node, 16-edge MFMA tiles ----------
// Lane roles: esl = lane&15 = edge slot in tile; hi = lane>>4.
// Lane's channels: c = 16*b + 4*hi + r  (b=0..7 block, r=0..3)  [= MFMA D-layout rows].
__global__ __launch_bounds__(256) void edge_flash(const int2* __restrict__ slotsrc,
                                                  const int* __restrict__ off,
                                                  const unsigned short* __restrict__ attrb,
                                                  const unsigned short* __restrict__ wefrag,
                                                  const float* __restrict__ Y,
                                                  float* __restrict__ agg, int Nn) {
  int wv = threadIdx.x >> 6, lane = threadIdx.x & 63;
  int node = blockIdx.x * 4 + wv;
  if (node >= Nn) return;
  int esl = lane & 15, hi = lane >> 4;

  // We A-fragments (bf16, prepacked)
  short8 weF[8];
#pragma unroll
  for (int b = 0; b < 8; ++b)
    weF[b] = *(const short8*)(wefrag + ((b * 64 + lane) << 3));

  // q preload in lane-channel layout, pre-scaled by (1/sqrt(32))*log2(e)
  float qv[8][4];
  const float* qrow = Y + (size_t)node * 768;
#pragma unroll
  for (int b = 0; b < 8; ++b) {
    float4 tq = *(const float4*)(qrow + 16 * b + 4 * hi);
    qv[b][0] = tq.x * 0.25505654f;
    qv[b][1] = tq.y * 0.25505654f;
    qv[b][2] = tq.z * 0.25505654f;
    qv[b][3] = tq.w * 0.25505654f;
  }

  float m[4], den[4], agr[8][4];
#pragma unroll
  for (int h = 0; h < 4; ++h) { m[h] = -INFINITY; den[h] = 0.0f; }
#pragma unroll
  for (int b = 0; b < 8; ++b)
#pragma unroll
    for (int r = 0; r < 4; ++r) agr[b][r] = 0.0f;

  int beg = off[node], end = off[node + 1];
  for (int p0 = beg; p0 < end; p0 += 16) {
    int pidx = p0 + esl;
    bool valid = pidx < end;
    if (!valid) pidx = end - 1;
    int2 ss = slotsrc[pidx];

    // attr B-fragment (edge = esl)
    short8 fb = (short8){0, 0, 0, 0, 0, 0, 0, 0};
    if (hi < 2) fb = *(const short8*)(attrb + ((size_t)ss.x << 4) + (hi << 3));

    // E^T = We^T @ attr^T : lane holds E[c, e=esl] for its 32 channels
    f32x4 accE[8];
#pragma unroll
    for (int b = 0; b < 8; ++b) {
      f32x4 z = {0.0f, 0.0f, 0.0f, 0.0f};
      accE[b] = __builtin_amdgcn_mfma_f32_16x16x32_bf16(weF[b], fb, z, 0, 0, 0);
    }

    // k gather + per-head dot partials
    const char* kvb = (const char*)Y + (size_t)ss.y * 3072 + 512 + (hi << 3);
    float ph[4] = {0.0f, 0.0f, 0.0f, 0.0f};
#pragma unroll
    for (int b = 0; b < 8; ++b) {
      ushort4 kk = *(const ushort4*)(kvb + (b << 5));
      int h = b >> 1;
      ph[h] = fmaf(qv[b][0], bf2f(kk.x) + accE[b][0], ph[h]);
      ph[h] = fmaf(qv[b][1], bf2f(kk.y) + accE[b][1], ph[h]);
      ph[h] = fmaf(qv[b][2], bf2f(kk.z) + accE[b][2], ph[h]);
      ph[h] = fmaf(qv[b][3], bf2f(kk.w) + accE[b][3], ph[h]);
    }
    // reduce over hi lanes -> full alpha (log2 domain) on every lane
#pragma unroll
    for (int h = 0; h < 4; ++h) {
      ph[h] += __shfl_xor(ph[h], 16);
      ph[h] += __shfl_xor(ph[h], 32);
      if (!valid) ph[h] = -3.0e38f;
    }
    // tile max + online softmax bookkeeping
    float p[4], sc[4];
#pragma unroll
    for (int h = 0; h < 4; ++h) {
      float tm = ph[h];
      tm = fmaxf(tm, __shfl_xor(tm, 1));
      tm = fmaxf(tm, __shfl_xor(tm, 2));
      tm = fmaxf(tm, __shfl_xor(tm, 4));
      tm = fmaxf(tm, __shfl_xor(tm, 8));
      float mn = fmaxf(m[h], tm);
      sc[h] = exp2f(m[h] - mn);
      p[h] = exp2f(ph[h] - mn);
      m[h] = mn;
      den[h] = den[h] * sc[h] + p[h];
    }
    // v gather + in-lane PV accumulate
#pragma unroll
    for (int b = 0; b < 8; ++b) {
      ushort4 vv = *(const ushort4*)(kvb + 256 + (b << 5));
      int h = b >> 1;
      float pr = p[h], s = sc[h];
      agr[b][0] = agr[b][0] * s + pr * (bf2f(vv.x) + accE[b][0]);
      agr[b][1] = agr[b][1] * s + pr * (bf2f(vv.y) + accE[b][1]);
      agr[b][2] = agr[b][2] * s + pr * (bf2f(vv.z) + accE[b][2]);
      agr[b][3] = agr[b][3] * s + pr * (bf2f(vv.w) + accE[b][3]);
    }
  }

  // epilogue: reduce den/agg over the 16 edge-slot lanes (within hi-group)
#pragma unroll
  for (int h = 0; h < 4; ++h) {
    den[h] += __shfl_xor(den[h], 1);
    den[h] += __shfl_xor(den[h], 2);
    den[h] += __shfl_xor(den[h], 4);
    den[h] += __shfl_xor(den[h], 8);
  }
#pragma unroll
  for (int b = 0; b < 8; ++b)
#pragma unroll
    for (int r = 0; r < 4; ++r) {
      agr[b][r] += __shfl_xor(agr[b][r], 1);
      agr[b][r] += __shfl_xor(agr[b][r], 2);
      agr[b][r] += __shfl_xor(agr[b][r], 4);
      agr[b][r] += __shfl_xor(agr[b][r], 8);
    }
  float rden[4];
#pragma unroll
  for (int h = 0; h < 4; ++h) rden[h] = 1.0f / (den[h] + 1e-16f);

  // each lane stores 2 channels: ids esl*2, esl*2+1 (static-index select to avoid scratch)
  int id0 = esl * 2;
  float v0 = 0.0f, v1 = 0.0f;
#pragma unroll
  for (int b = 0; b < 8; ++b)
#pragma unroll
    for (int r = 0; r < 4; ++r) {
      int id = b * 4 + r;
      float tv = agr[b][r] * rden[b >> 1];
      if (id == id0) v0 = tv;
      if (id == id0 + 1) v1 = tv;
    }
  int c0 = (id0 >> 2) * 16 + hi * 4 + (id0 & 3);
  float* arow = agg + (size_t)node * 128;
  arow[c0] = v0;
  arow[c0 + 1] = v1;
}

// ---------- LN1 + GELU ----------
__global__ __launch_bounds__(256) void ln_gelu_kernel(const float* __restrict__ agg,
                                                      const float* __restrict__ Y,
                                                      const float* __restrict__ g1,
                                                      const float* __restrict__ b1,
                                                      float* __restrict__ u,
                                                      unsigned short* __restrict__ ub, int Nn) {
  int w = threadIdx.x >> 6, lane = threadIdx.x & 63;
  int row = blockIdx.x * 4 + w;
  if (row >= Nn) return;
  const float* yrow = Y + (size_t)row * 768 + 384;  // xs segment
  const float* arow = agg + (size_t)row * 128;
  float h0 = arow[lane] + yrow[lane];
  float h1 = arow[lane + 64] + yrow[lane + 64];
  float s = h0 + h1;
#pragma unroll
  for (int o = 32; o; o >>= 1) s += __shfl_xor(s, o, 64);
  float mean = s * (1.0f / 128.0f);
  float d0 = h0 - mean, d1 = h1 - mean;
  float ss = d0 * d0 + d1 * d1;
#pragma unroll
  for (int o = 32; o; o >>= 1) ss += __shfl_xor(ss, o, 64);
  float rs = rsqrtf(ss * (1.0f / 128.0f) + 1e-5f);
  float y0 = d0 * rs * g1[lane] + b1[lane];
  float y1 = d1 * rs * g1[lane + 64] + b1[lane + 64];
  float u0 = 0.5f * y0 * (1.0f + erff(y0 * 0.7071067811865475f));
  float u1 = 0.5f * y1 * (1.0f + erff(y1 * 0.7071067811865475f));
  size_t base = (size_t)row * 128;
  u[base + lane] = u0;
  u[base + lane + 64] = u1;
  ub[base + lane] = f2bf(u0);
  ub[base + lane + 64] = f2bf(u1);
}

// ---------- gate + LN2 -> out ----------
__global__ __launch_bounds__(256) void gate_ln_kernel(const float* __restrict__ gate_u,
                                                      const float* __restrict__ Y,
                                                      const float* __restrict__ u,
                                                      const float* __restrict__ g2,
                                                      const float* __restrict__ b2,
                                                      float* __restrict__ out, int Nn) {
  int w = threadIdx.x >> 6, lane = threadIdx.x & 63;
  int row = blockIdx.x * 4 + w;
  if (row >= Nn) return;
  const float* yrow = Y + (size_t)row * 768;
  size_t base = (size_t)row * 128;
  float z0 = gate_u[base + lane] + yrow[640 + lane];            // gate_x (has bg)
  float z1 = gate_u[base + lane + 64] + yrow[640 + lane + 64];
  float gg0 = 1.0f / (1.0f + __expf(-z0));
  float gg1 = 1.0f / (1.0f + __expf(-z1));
  float u0 = u[base + lane], u1 = u[base + lane + 64];
  float s0 = yrow[512 + lane], s1 = yrow[512 + lane + 64];      // skip
  float h0 = gg0 * u0 + (1.0f - gg0) * s0;
  float h1 = gg1 * u1 + (1.0f - gg1) * s1;
  float s = h0 + h1;
#pragma unroll
  for (int o = 32; o; o >>= 1) s += __shfl_xor(s, o, 64);
  float mean = s * (1.0f / 128.0f);
  float d0 = h0 - mean, d1 = h1 - mean;
  float ss = d0 * d0 + d1 * d1;
#pragma unroll
  for (int o = 32; o; o >>= 1) ss += __shfl_xor(ss, o, 64);
  float rs = rsqrtf(ss * (1.0f / 128.0f) + 1e-5f);
  out[base + lane] = d0 * rs * g2[lane] + b2[lane];
  out[base + lane + 64] = d1 * rs * g2[lane + 64] + b2[lane + 64];
}

// ---------- launch ----------
extern "C" void kernel_launch(void* const* d_in, const int* in_sizes, int n_in,
                              void* d_out, int out_size, void* d_ws, size_t ws_size,
                              hipStream_t stream) {
  const float* x = (const float*)d_in[0];
  const int* edge_index = (const int*)d_in[1];
  const float* edge_attr = (const float*)d_in[2];
  const float* Wq = (const float*)d_in[3];
  const float* bq = (const float*)d_in[4];
  const float* Wk = (const float*)d_in[5];
  const float* bk = (const float*)d_in[6];
  const float* Wv = (const float*)d_in[7];
  const float* bv = (const float*)d_in[8];
  const float* We = (const float*)d_in[9];
  const float* Ws = (const float*)d_in[10];
  const float* bs = (const float*)d_in[11];
  const float* Wsp = (const float*)d_in[12];
  const float* bsp = (const float*)d_in[13];
  const float* Wg = (const float*)d_in[14];
  const float* bg = (const float*)d_in[15];
  const float* g1 = (const float*)d_in[16];
  const float* b1 = (const float*)d_in[17];
  const float* g2 = (const float*)d_in[18];
  const float* b2 = (const float*)d_in[19];

  int Nn = in_sizes[0] / 128;
  int E = in_sizes[1] / 2;

  char* p = (char*)d_ws;
  auto align256 = [](size_t b) { return (b + 255) & ~(size_t)255; };
  auto alloc = [&](size_t bytes) -> char* {
    char* r = p;
    p += align256(bytes);
    return r;
  };
  // ---- persistent buffers ----
  float* Y = (float*)alloc((size_t)Nn * 768 * 4);       // q | bf16 kv | xs | skip | gate_x
  float* agg = (float*)alloc((size_t)Nn * 128 * 4);
  unsigned short* WcatT = (unsigned short*)alloc(768 * 128 * 2);
  unsigned short* WgTopT = (unsigned short*)alloc(128 * 128 * 2);
  unsigned short* wefrag = (unsigned short*)alloc(4096 * 2);
  float* bcat = (float*)alloc(768 * 4);
  int* off = (int*)alloc((size_t)(Nn + 1) * 4);

  // ---- overlay arena: "early" buffers (dead after edge_flash) share memory with
  //      "late" buffers (first written after edge_flash). ----
  size_t earlySz = align256((size_t)Nn * 128 * 2)   // xb
                 + align256((size_t)E * 16 * 2)     // attrb
                 + align256((size_t)E * 8)          // slotsrc
                 + align256((size_t)Nn * 4)         // deg
                 + align256((size_t)Nn * 4)         // cursor
                 + align256(256 * 4);               // bsum
  size_t lateSz = align256((size_t)Nn * 128 * 4)    // u
                + align256((size_t)Nn * 128 * 2)    // ub
                + align256((size_t)Nn * 128 * 4);   // gate_u
  char* arena = alloc(earlySz > lateSz ? earlySz : lateSz);

  char* q = arena;
  auto ealloc = [&](size_t bytes) -> char* { char* r = q; q += align256(bytes); return r; };
  unsigned short* xb = (unsigned short*)ealloc((size_t)Nn * 128 * 2);
  unsigned short* attrb = (unsigned short*)ealloc((size_t)E * 16 * 2);
  int2* slotsrc = (int2*)ealloc((size_t)E * 8);
  int* deg = (int*)ealloc((size_t)Nn * 4);
  int* cursor = (int*)ealloc((size_t)Nn * 4);
  int* bsum = (int*)ealloc(256 * 4);

  q = arena;  // late overlay
  float* u = (float*)ealloc((size_t)Nn * 128 * 4);
  unsigned short* ub = (unsigned short*)ealloc((size_t)Nn * 128 * 2);
  float* gate_u = (float*)ealloc((size_t)Nn * 128 * 4);

  hipMemsetAsync(deg, 0, (size_t)Nn * 4, stream);
  prep_weights<<<(768 * 128 + 255) / 256, 256, 0, stream>>>(Wq, bq, Wk, bk, Wv, bv, Ws, bs,
                                                            Wsp, bsp, Wg, bg, WcatT, WgTopT, bcat);
  prep_wefrag<<<16, 256, 0, stream>>>(We, wefrag);
  convert_bf16<<<((Nn * 128 / 4) + 255) / 256, 256, 0, stream>>>(x, xb, Nn * 128 / 4);
  convert_bf16<<<((E * 16 / 4) + 255) / 256, 256, 0, stream>>>(edge_attr, attrb, E * 16 / 4);
  count_deg<<<(E + 255) / 256, 256, 0, stream>>>(edge_index + E, deg, E);

  int G = (Nn + 1023) >> 10;
  scan_bsum<<<G, 256, 0, stream>>>(deg, bsum, Nn);
  scan_top<<<1, 64, 0, stream>>>(bsum, G);
  scan_write<<<G, 256, 0, stream>>>(deg, bsum, off, cursor, Nn);
  scatter_kernel<<<(E + 255) / 256, 256, 0, stream>>>(edge_index, cursor, slotsrc, E);

  gemm_fused<<<(Nn + 127) / 128, 256, 0, stream>>>(xb, WcatT, bcat, Y, Nn);

  edge_flash<<<(Nn + 3) / 4, 256, 0, stream>>>(slotsrc, off, attrb, wefrag, Y, agg, Nn);

  ln_gelu_kernel<<<(Nn + 3) / 4, 256, 0, stream>>>(agg, Y, g1, b1, u, ub, Nn);

  gemm_single<<<(Nn + 127) / 128, 256, 0, stream>>>(ub, WgTopT, gate_u, Nn);

  gate_ln_kernel<<<(Nn + 3) / 4, 256, 0, stream>>>(gate_u, Y, u, g2, b2, (float*)d_out, Nn);
}

// Round 5
// 402.433 us; speedup vs baseline: 1.6726x; 1.1380x over previous
//
#include <hip/hip_runtime.h>
#include <hip/hip_bf16.h>

// ---------- helpers ----------
typedef short short8 __attribute__((ext_vector_type(8)));
typedef float f32x4 __attribute__((ext_vector_type(4)));

__device__ inline unsigned short f2bf(float x) {
  union { float f; unsigned u; } un; un.f = x;
  unsigned r = un.u + 0x7FFFu + ((un.u >> 16) & 1u);
  return (unsigned short)(r >> 16);
}
__device__ inline float bf2f(unsigned short u) {
  union { unsigned u; float f; } un; un.u = ((unsigned)u) << 16; return un.f;
}

// ---------- weight prep: WcatT [768][128] bf16 (row n = output col), WgTopT [128][128], bcat[768] ----------
__global__ void prep_weights(const float* __restrict__ Wq, const float* __restrict__ bq,
                             const float* __restrict__ Wk, const float* __restrict__ bk,
                             const float* __restrict__ Wv, const float* __restrict__ bv,
                             const float* __restrict__ Ws, const float* __restrict__ bs,
                             const float* __restrict__ Wsp, const float* __restrict__ bsp,
                             const float* __restrict__ Wg, const float* __restrict__ bg,
                             unsigned short* __restrict__ WcatT, unsigned short* __restrict__ WgTopT,
                             float* __restrict__ bcat) {
  int tid = blockIdx.x * 256 + threadIdx.x;
  if (tid >= 768 * 128) return;
  int n = tid >> 7, k = tid & 127;
  int s = n >> 7, c = n & 127;
  float val;
  if (s == 0) val = Wq[k * 128 + c];
  else if (s == 1) val = Wk[k * 128 + c];
  else if (s == 2) val = Wv[k * 128 + c];
  else if (s == 3) val = Ws[k * 128 + c];
  else if (s == 4) val = Wsp[k * 128 + c];
  else val = Wg[(128 + k) * 128 + c];   // bottom half of Wg (x part of concat)
  WcatT[tid] = f2bf(val);
  if (n < 128) WgTopT[n * 128 + k] = f2bf(Wg[k * 128 + n]);  // top half of Wg, transposed
  if (k == 0) {
    float bv2;
    if (s == 0) bv2 = bq[c]; else if (s == 1) bv2 = bk[c]; else if (s == 2) bv2 = bv[c];
    else if (s == 3) bv2 = bs[c]; else if (s == 4) bv2 = bsp[c]; else bv2 = bg[c];
    bcat[n] = bv2;
  }
}

// ---------- We MFMA A-fragment table: wf[(b*64+lane)*8+j] = We[t][b*16+(lane&15)], t=(lane>>4)*8+j (<16) ----------
__global__ void prep_wefrag(const float* __restrict__ We, unsigned short* __restrict__ wf) {
  int id = blockIdx.x * 256 + threadIdx.x;
  if (id >= 4096) return;
  int j = id & 7, lane = (id >> 3) & 63, b = id >> 9;
  int t = (lane >> 4) * 8 + j;
  float v = (t < 16) ? We[t * 128 + b * 16 + (lane & 15)] : 0.0f;
  wf[id] = f2bf(v);
}

__global__ void convert_bf16(const float* __restrict__ x, unsigned short* __restrict__ xb, int n4) {
  int i = blockIdx.x * 256 + threadIdx.x;
  if (i < n4) {
    float4 v = ((const float4*)x)[i];
    ushort4 o;
    o.x = f2bf(v.x); o.y = f2bf(v.y); o.z = f2bf(v.z); o.w = f2bf(v.w);
    ((ushort4*)xb)[i] = o;
  }
}

// ---------- CSR build ----------
__global__ void count_deg(const int* __restrict__ dst, int* __restrict__ deg, int E) {
  int i = blockIdx.x * 256 + threadIdx.x;
  if (i < E) atomicAdd(&deg[dst[i]], 1);
}

__global__ __launch_bounds__(256) void scan_bsum(const int* __restrict__ deg, int* __restrict__ bsum, int n) {
  __shared__ int red[256];
  int b = blockIdx.x, t = threadIdx.x;
  int base = b * 1024 + t * 4;
  int s = 0;
#pragma unroll
  for (int j = 0; j < 4; ++j) { int i = base + j; if (i < n) s += deg[i]; }
  red[t] = s; __syncthreads();
  for (int o = 128; o; o >>= 1) { if (t < o) red[t] += red[t + o]; __syncthreads(); }
  if (t == 0) bsum[b] = red[0];
}

__global__ void scan_top(int* __restrict__ bsum, int G) {  // 64 threads, G<=64
  int lane = threadIdx.x;
  int v = (lane < G) ? bsum[lane] : 0;
  int orig = v;
#pragma unroll
  for (int d = 1; d < 64; d <<= 1) { int u = __shfl_up(v, d); if (lane >= d) v += u; }
  if (lane < G) bsum[lane] = v - orig;   // exclusive block base
}

__global__ __launch_bounds__(256) void scan_write(const int* __restrict__ deg, const int* __restrict__ bsum,
                                                  int* __restrict__ off, int* __restrict__ cursor, int n) {
  __shared__ int red[256];
  int b = blockIdx.x, t = threadIdx.x;
  int base = b * 1024 + t * 4;
  int d0 = 0, d1 = 0, d2 = 0, d3 = 0;
  if (base + 3 < n) {
    int4 d4 = *(const int4*)(deg + base);
    d0 = d4.x; d1 = d4.y; d2 = d4.z; d3 = d4.w;
  } else {
    if (base + 0 < n) d0 = deg[base + 0];
    if (base + 1 < n) d1 = deg[base + 1];
    if (base + 2 < n) d2 = deg[base + 2];
    if (base + 3 < n) d3 = deg[base + 3];
  }
  int tsum = d0 + d1 + d2 + d3;
  red[t] = tsum; __syncthreads();
  for (int o = 1; o < 256; o <<= 1) {
    int val = (t >= o) ? red[t - o] : 0;
    __syncthreads();
    red[t] += val;
    __syncthreads();
  }
  int run = bsum[b] + red[t] - tsum;
  if (base + 0 < n) { off[base + 0] = run; cursor[base + 0] = run; run += d0; }
  if (base + 1 < n) { off[base + 1] = run; cursor[base + 1] = run; run += d1; }
  if (base + 2 < n) { off[base + 2] = run; cursor[base + 2] = run; run += d2; }
  if (base + 3 < n) { off[base + 3] = run; cursor[base + 3] = run; run += d3; }
  if (b == gridDim.x - 1 && t == 255) off[n] = run;
}

// store (eid, src) packed so the hot loop has no indirection
__global__ void scatter_kernel(const int* __restrict__ ei, int* __restrict__ cursor,
                               int2* __restrict__ slotsrc, int E) {
  int i = blockIdx.x * 256 + threadIdx.x;
  if (i < E) {
    int s = ei[i];
    int d = ei[E + i];
    int p = atomicAdd(&cursor[d], 1);
    slotsrc[p] = make_int2(i, s);
  }
}

// ---------- fused 6-block GEMM: Y[M,768] = xb[M,128] @ WcatT^T + bcat ----------
// nb==1,2 (k/v segments) written as packed bf16 into bytes 512..1023 of each Y row.
__global__ __launch_bounds__(256) void gemm_fused(const unsigned short* __restrict__ A,
                                                  const unsigned short* __restrict__ BT,
                                                  const float* __restrict__ bias,
                                                  float* __restrict__ Y, int M) {
  __shared__ char As[32768];
  __shared__ char Bs[32768];
  int m0 = blockIdx.x * 128;
  int t = threadIdx.x;
  {
    int row = t >> 1;
    int hb = (t & 1) * 128;
    const char* srow = (const char*)(A + (size_t)(m0 + row) * 128);
    bool ok = (m0 + row) < M;
    char* lrow = As + row * 256;
    int sw = (row & 7) << 4;
#pragma unroll
    for (int j = 0; j < 8; ++j) {
      int b = hb + j * 16;
      uint4 val;
      if (ok) val = *(const uint4*)(srow + b);
      else { val.x = 0; val.y = 0; val.z = 0; val.w = 0; }
      *(uint4*)(lrow + (b ^ sw)) = val;
    }
  }
  int w = t >> 6, lane = t & 63;
  int lm = lane & 15, hi = lane >> 4;
  for (int nb = 0; nb < 6; ++nb) {
    __syncthreads();
    {
      int row = t >> 1;
      int hb = (t & 1) * 128;
      const char* srow = (const char*)(BT + (size_t)(nb * 128 + row) * 128);
      char* lrow = Bs + row * 256;
      int sw = (row & 7) << 4;
#pragma unroll
      for (int j = 0; j < 8; ++j) {
        int b = hb + j * 16;
        uint4 val = *(const uint4*)(srow + b);
        *(uint4*)(lrow + (b ^ sw)) = val;
      }
    }
    __syncthreads();
    f32x4 acc[2][8] = {};
#pragma unroll
    for (int kb = 0; kb < 4; ++kb) {
      int colb = kb * 64 + hi * 16;
      short8 a[2];
#pragma unroll
      for (int rf = 0; rf < 2; ++rf) {
        int row = w * 32 + rf * 16 + lm;
        a[rf] = *(const short8*)(As + row * 256 + (colb ^ ((row & 7) << 4)));
      }
#pragma unroll
      for (int cf = 0; cf < 8; ++cf) {
        int row = cf * 16 + lm;
        short8 bfr = *(const short8*)(Bs + row * 256 + (colb ^ ((row & 7) << 4)));
        acc[0][cf] = __builtin_amdgcn_mfma_f32_16x16x32_bf16(a[0], bfr, acc[0][cf], 0, 0, 0);
        acc[1][cf] = __builtin_amdgcn_mfma_f32_16x16x32_bf16(a[1], bfr, acc[1][cf], 0, 0, 0);
      }
    }
    bool to16 = (nb == 1 || nb == 2);
#pragma unroll
    for (int rf = 0; rf < 2; ++rf) {
#pragma unroll
      for (int cf = 0; cf < 8; ++cf) {
        int col = nb * 128 + cf * 16 + lm;
        float bv = bias[col];
#pragma unroll
        for (int j = 0; j < 4; ++j) {
          int row = m0 + w * 32 + rf * 16 + hi * 4 + j;
          if (row < M) {
            float val = acc[rf][cf][j] + bv;
            if (to16) {
              unsigned short* kvrow = (unsigned short*)((char*)Y + (size_t)row * 3072 + 512);
              kvrow[col - 128] = f2bf(val);
            } else {
              Y[(size_t)row * 768 + col] = val;
            }
          }
        }
      }
    }
  }
}

// ---------- plain 128-col GEMM (for gate top): C[M,128] = A[M,128] @ BT^T ----------
__global__ __launch_bounds__(256) void gemm_single(const unsigned short* __restrict__ A,
                                                   const unsigned short* __restrict__ BT,
                                                   float* __restrict__ C, int M) {
  __shared__ char As[32768];
  __shared__ char Bs[32768];
  int m0 = blockIdx.x * 128;
  int t = threadIdx.x;
  {
    int row = t >> 1;
    int hb = (t & 1) * 128;
    const char* srow = (const char*)(A + (size_t)(m0 + row) * 128);
    bool ok = (m0 + row) < M;
    char* lrow = As + row * 256;
    int sw = (row & 7) << 4;
#pragma unroll
    for (int j = 0; j < 8; ++j) {
      int b = hb + j * 16;
      uint4 val;
      if (ok) val = *(const uint4*)(srow + b);
      else { val.x = 0; val.y = 0; val.z = 0; val.w = 0; }
      *(uint4*)(lrow + (b ^ sw)) = val;
    }
  }
  {
    int row = t >> 1;
    int hb = (t & 1) * 128;
    const char* srow = (const char*)(BT + (size_t)row * 128);
    char* lrow = Bs + row * 256;
    int sw = (row & 7) << 4;
#pragma unroll
    for (int j = 0; j < 8; ++j) {
      int b = hb + j * 16;
      uint4 val = *(const uint4*)(srow + b);
      *(uint4*)(lrow + (b ^ sw)) = val;
    }
  }
  __syncthreads();
  int w = t >> 6, lane = t & 63;
  int lm = lane & 15, hi = lane >> 4;
  f32x4 acc[2][8] = {};
#pragma unroll
  for (int kb = 0; kb < 4; ++kb) {
    int colb = kb * 64 + hi * 16;
    short8 a[2];
#pragma unroll
    for (int rf = 0; rf < 2; ++rf) {
      int row = w * 32 + rf * 16 + lm;
      a[rf] = *(const short8*)(As + row * 256 + (colb ^ ((row & 7) << 4)));
    }
#pragma unroll
    for (int cf = 0; cf < 8; ++cf) {
      int row = cf * 16 + lm;
      short8 bfr = *(const short8*)(Bs + row * 256 + (colb ^ ((row & 7) << 4)));
      acc[0][cf] = __builtin_amdgcn_mfma_f32_16x16x32_bf16(a[0], bfr, acc[0][cf], 0, 0, 0);
      acc[1][cf] = __builtin_amdgcn_mfma_f32_16x16x32_bf16(a[1], bfr, acc[1][cf], 0, 0, 0);
    }
  }
#pragma unroll
  for (int rf = 0; rf < 2; ++rf) {
#pragma unroll
    for (int cf = 0; cf < 8; ++cf) {
      int col = cf * 16 + lm;
#pragma unroll
      for (int j = 0; j < 4; ++j) {
        int row = m0 + w * 32 + rf * 16 + hi * 4 + j;
        if (row < M) C[(size_t)row * 128 + col] = acc[rf][cf][j];
      }
    }
  }
}

// ---------- node-centric flash edge aggregation: 1 wave = (node, half of channels) ----------
// Half hf owns channels hf*64 + 16*bp + 4*hi + r (bp=0..3) = heads {2hf, 2hf+1}.
// Lane roles: esl = lane&15 = edge slot in 16-edge tile; hi = lane>>4.
__global__ __launch_bounds__(256) void edge_flash(const int2* __restrict__ slotsrc,
                                                  const int* __restrict__ off,
                                                  const unsigned short* __restrict__ attrb,
                                                  const unsigned short* __restrict__ wefrag,
                                                  const float* __restrict__ Y,
                                                  float* __restrict__ agg, int Nn) {
  int wv = threadIdx.x >> 6, lane = threadIdx.x & 63;
  int node = blockIdx.x * 2 + (wv >> 1);
  if (node >= Nn) return;
  int hf = wv & 1;
  int esl = lane & 15, hi = lane >> 4;

  // We A-fragments for this half's 4 channel-blocks
  short8 weF[4];
#pragma unroll
  for (int bp = 0; bp < 4; ++bp)
    weF[bp] = *(const short8*)(wefrag + (((hf * 4 + bp) * 64 + lane) << 3));

  // q preload (this half's channels), pre-scaled by (1/sqrt(32))*log2(e)
  float qv[4][4];
  const float* qrow = Y + (size_t)node * 768 + hf * 64;
#pragma unroll
  for (int bp = 0; bp < 4; ++bp) {
    float4 tq = *(const float4*)(qrow + 16 * bp + 4 * hi);
    qv[bp][0] = tq.x * 0.25505654f;
    qv[bp][1] = tq.y * 0.25505654f;
    qv[bp][2] = tq.z * 0.25505654f;
    qv[bp][3] = tq.w * 0.25505654f;
  }

  float m[2], den[2], agr[4][4];
#pragma unroll
  for (int h = 0; h < 2; ++h) { m[h] = -INFINITY; den[h] = 0.0f; }
#pragma unroll
  for (int bp = 0; bp < 4; ++bp)
#pragma unroll
    for (int r = 0; r < 4; ++r) agr[bp][r] = 0.0f;

  int beg = off[node], end = off[node + 1];

  // prefetch tile-0 slot/src
  int2 ssA;
  if (beg < end) {
    int idx = beg + esl; if (idx >= end) idx = end - 1;
    ssA = slotsrc[idx];
  }
  for (int p0 = beg; p0 < end; p0 += 16) {
    int2 ss = ssA;
    bool valid = (p0 + esl) < end;
    // prefetch next tile's slot/src
    if (p0 + 16 < end) {
      int idx = p0 + 16 + esl; if (idx >= end) idx = end - 1;
      ssA = slotsrc[idx];
    }
    // issue k/v gathers early (latency overlapped by MFMA below)
    const char* kvb = (const char*)Y + (size_t)ss.y * 3072 + 512 + hf * 128 + (hi << 3);
    ushort4 kk[4], vv[4];
#pragma unroll
    for (int bp = 0; bp < 4; ++bp) {
      kk[bp] = *(const ushort4*)(kvb + (bp << 5));
      vv[bp] = *(const ushort4*)(kvb + 256 + (bp << 5));
    }
    // attr B-fragment (edge = esl): hi 0,1 hold the 16 attr dims, hi 2,3 zero
    short8 fb = (short8){0, 0, 0, 0, 0, 0, 0, 0};
    if (hi < 2) fb = *(const short8*)(attrb + ((size_t)ss.x << 4) + (hi << 3));

    // E^T = We^T @ attr^T : lane holds E[c, e=esl] for its 16 channels
    f32x4 accE[4];
#pragma unroll
    for (int bp = 0; bp < 4; ++bp) {
      f32x4 z = {0.0f, 0.0f, 0.0f, 0.0f};
      accE[bp] = __builtin_amdgcn_mfma_f32_16x16x32_bf16(weF[bp], fb, z, 0, 0, 0);
    }

    // per-head dot partials (local heads 0,1 = global 2hf, 2hf+1)
    float ph[2] = {0.0f, 0.0f};
#pragma unroll
    for (int bp = 0; bp < 4; ++bp) {
      int h = bp >> 1;
      ph[h] = fmaf(qv[bp][0], bf2f(kk[bp].x) + accE[bp][0], ph[h]);
      ph[h] = fmaf(qv[bp][1], bf2f(kk[bp].y) + accE[bp][1], ph[h]);
      ph[h] = fmaf(qv[bp][2], bf2f(kk[bp].z) + accE[bp][2], ph[h]);
      ph[h] = fmaf(qv[bp][3], bf2f(kk[bp].w) + accE[bp][3], ph[h]);
    }
    // reduce over hi lanes -> full alpha (log2 domain) on every lane
#pragma unroll
    for (int h = 0; h < 2; ++h) {
      ph[h] += __shfl_xor(ph[h], 16);
      ph[h] += __shfl_xor(ph[h], 32);
      if (!valid) ph[h] = -3.0e38f;
    }
    // tile max + online softmax bookkeeping
    float p[2], sc[2];
#pragma unroll
    for (int h = 0; h < 2; ++h) {
      float tm = ph[h];
      tm = fmaxf(tm, __shfl_xor(tm, 1));
      tm = fmaxf(tm, __shfl_xor(tm, 2));
      tm = fmaxf(tm, __shfl_xor(tm, 4));
      tm = fmaxf(tm, __shfl_xor(tm, 8));
      float mn = fmaxf(m[h], tm);
      sc[h] = exp2f(m[h] - mn);
      p[h] = exp2f(ph[h] - mn);
      m[h] = mn;
      den[h] = den[h] * sc[h] + p[h];
    }
    // in-lane PV accumulate
#pragma unroll
    for (int bp = 0; bp < 4; ++bp) {
      int h = bp >> 1;
      float pr = p[h], s = sc[h];
      agr[bp][0] = agr[bp][0] * s + pr * (bf2f(vv[bp].x) + accE[bp][0]);
      agr[bp][1] = agr[bp][1] * s + pr * (bf2f(vv[bp].y) + accE[bp][1]);
      agr[bp][2] = agr[bp][2] * s + pr * (bf2f(vv[bp].z) + accE[bp][2]);
      agr[bp][3] = agr[bp][3] * s + pr * (bf2f(vv[bp].w) + accE[bp][3]);
    }
  }

  // epilogue: reduce den/agg over the 16 edge-slot lanes (intra-16 xor -> DPP-friendly)
#pragma unroll
  for (int h = 0; h < 2; ++h) {
    den[h] += __shfl_xor(den[h], 1);
    den[h] += __shfl_xor(den[h], 2);
    den[h] += __shfl_xor(den[h], 4);
    den[h] += __shfl_xor(den[h], 8);
  }
#pragma unroll
  for (int bp = 0; bp < 4; ++bp)
#pragma unroll
    for (int r = 0; r < 4; ++r) {
      agr[bp][r] += __shfl_xor(agr[bp][r], 1);
      agr[bp][r] += __shfl_xor(agr[bp][r], 2);
      agr[bp][r] += __shfl_xor(agr[bp][r], 4);
      agr[bp][r] += __shfl_xor(agr[bp][r], 8);
    }
  float rden[2];
#pragma unroll
  for (int h = 0; h < 2; ++h) rden[h] = 1.0f / (den[h] + 1e-16f);

  // each lane stores 1 channel: (bp = esl>>2, r = esl&3)
  float v0 = 0.0f;
#pragma unroll
  for (int bp = 0; bp < 4; ++bp)
#pragma unroll
    for (int r = 0; r < 4; ++r) {
      int id = bp * 4 + r;
      float tv = agr[bp][r] * rden[bp >> 1];
      if (id == esl) v0 = tv;
    }
  int c = hf * 64 + (esl >> 2) * 16 + hi * 4 + (esl & 3);
  agg[(size_t)node * 128 + c] = v0;
}

// ---------- LN1 + GELU ----------
__global__ __launch_bounds__(256) void ln_gelu_kernel(const float* __restrict__ agg,
                                                      const float* __restrict__ Y,
                                                      const float* __restrict__ g1,
                                                      const float* __restrict__ b1,
                                                      float* __restrict__ u,
                                                      unsigned short* __restrict__ ub, int Nn) {
  int w = threadIdx.x >> 6, lane = threadIdx.x & 63;
  int row = blockIdx.x * 4 + w;
  if (row >= Nn) return;
  const float* yrow = Y + (size_t)row * 768 + 384;  // xs segment
  const float* arow = agg + (size_t)row * 128;
  float h0 = arow[lane] + yrow[lane];
  float h1 = arow[lane + 64] + yrow[lane + 64];
  float s = h0 + h1;
#pragma unroll
  for (int o = 32; o; o >>= 1) s += __shfl_xor(s, o, 64);
  float mean = s * (1.0f / 128.0f);
  float d0 = h0 - mean, d1 = h1 - mean;
  float ss = d0 * d0 + d1 * d1;
#pragma unroll
  for (int o = 32; o; o >>= 1) ss += __shfl_xor(ss, o, 64);
  float rs = rsqrtf(ss * (1.0f / 128.0f) + 1e-5f);
  float y0 = d0 * rs * g1[lane] + b1[lane];
  float y1 = d1 * rs * g1[lane + 64] + b1[lane + 64];
  float u0 = 0.5f * y0 * (1.0f + erff(y0 * 0.7071067811865475f));
  float u1 = 0.5f * y1 * (1.0f + erff(y1 * 0.7071067811865475f));
  size_t base = (size_t)row * 128;
  u[base + lane] = u0;
  u[base + lane + 64] = u1;
  ub[base + lane] = f2bf(u0);
  ub[base + lane + 64] = f2bf(u1);
}

// ---------- gate + LN2 -> out ----------
__global__ __launch_bounds__(256) void gate_ln_kernel(const float* __restrict__ gate_u,
                                                      const float* __restrict__ Y,
                                                      const float* __restrict__ u,
                                                      const float* __restrict__ g2,
                                                      const float* __restrict__ b2,
                                                      float* __restrict__ out, int Nn) {
  int w = threadIdx.x >> 6, lane = threadIdx.x & 63;
  int row = blockIdx.x * 4 + w;
  if (row >= Nn) return;
  const float* yrow = Y + (size_t)row * 768;
  size_t base = (size_t)row * 128;
  float z0 = gate_u[base + lane] + yrow[640 + lane];            // gate_x (has bg)
  float z1 = gate_u[base + lane + 64] + yrow[640 + lane + 64];
  float gg0 = 1.0f / (1.0f + __expf(-z0));
  float gg1 = 1.0f / (1.0f + __expf(-z1));
  float u0 = u[base + lane], u1 = u[base + lane + 64];
  float s0 = yrow[512 + lane], s1 = yrow[512 + lane + 64];      // skip
  float h0 = gg0 * u0 + (1.0f - gg0) * s0;
  float h1 = gg1 * u1 + (1.0f - gg1) * s1;
  float s = h0 + h1;
#pragma unroll
  for (int o = 32; o; o >>= 1) s += __shfl_xor(s, o, 64);
  float mean = s * (1.0f / 128.0f);
  float d0 = h0 - mean, d1 = h1 - mean;
  float ss = d0 * d0 + d1 * d1;
#pragma unroll
  for (int o = 32; o; o >>= 1) ss += __shfl_xor(ss, o, 64);
  float rs = rsqrtf(ss * (1.0f / 128.0f) + 1e-5f);
  out[base + lane] = d0 * rs * g2[lane] + b2[lane];
  out[base + lane + 64] = d1 * rs * g2[lane + 64] + b2[lane + 64];
}

// ---------- launch ----------
extern "C" void kernel_launch(void* const* d_in, const int* in_sizes, int n_in,
                              void* d_out, int out_size, void* d_ws, size_t ws_size,
                              hipStream_t stream) {
  const float* x = (const float*)d_in[0];
  const int* edge_index = (const int*)d_in[1];
  const float* edge_attr = (const float*)d_in[2];
  const float* Wq = (const float*)d_in[3];
  const float* bq = (const float*)d_in[4];
  const float* Wk = (const float*)d_in[5];
  const float* bk = (const float*)d_in[6];
  const float* Wv = (const float*)d_in[7];
  const float* bv = (const float*)d_in[8];
  const float* We = (const float*)d_in[9];
  const float* Ws = (const float*)d_in[10];
  const float* bs = (const float*)d_in[11];
  const float* Wsp = (const float*)d_in[12];
  const float* bsp = (const float*)d_in[13];
  const float* Wg = (const float*)d_in[14];
  const float* bg = (const float*)d_in[15];
  const float* g1 = (const float*)d_in[16];
  const float* b1 = (const float*)d_in[17];
  const float* g2 = (const float*)d_in[18];
  const float* b2 = (const float*)d_in[19];

  int Nn = in_sizes[0] / 128;
  int E = in_sizes[1] / 2;

  char* p = (char*)d_ws;
  auto align256 = [](size_t b) { return (b + 255) & ~(size_t)255; };
  auto alloc = [&](size_t bytes) -> char* {
    char* r = p;
    p += align256(bytes);
    return r;
  };
  // ---- persistent buffers ----
  float* Y = (float*)alloc((size_t)Nn * 768 * 4);       // q | bf16 kv | xs | skip | gate_x
  float* agg = (float*)alloc((size_t)Nn * 128 * 4);
  unsigned short* WcatT = (unsigned short*)alloc(768 * 128 * 2);
  unsigned short* WgTopT = (unsigned short*)alloc(128 * 128 * 2);
  unsigned short* wefrag = (unsigned short*)alloc(4096 * 2);
  float* bcat = (float*)alloc(768 * 4);
  int* off = (int*)alloc((size_t)(Nn + 1) * 4);

  // ---- overlay arena: "early" buffers (dead after edge_flash) share memory with
  //      "late" buffers (first written after edge_flash). ----
  size_t earlySz = align256((size_t)Nn * 128 * 2)   // xb
                 + align256((size_t)E * 16 * 2)     // attrb
                 + align256((size_t)E * 8)          // slotsrc
                 + align256((size_t)Nn * 4)         // deg
                 + align256((size_t)Nn * 4)         // cursor
                 + align256(256 * 4);               // bsum
  size_t lateSz = align256((size_t)Nn * 128 * 4)    // u
                + align256((size_t)Nn * 128 * 2)    // ub
                + align256((size_t)Nn * 128 * 4);   // gate_u
  char* arena = alloc(earlySz > lateSz ? earlySz : lateSz);

  char* q = arena;
  auto ealloc = [&](size_t bytes) -> char* { char* r = q; q += align256(bytes); return r; };
  unsigned short* xb = (unsigned short*)ealloc((size_t)Nn * 128 * 2);
  unsigned short* attrb = (unsigned short*)ealloc((size_t)E * 16 * 2);
  int2* slotsrc = (int2*)ealloc((size_t)E * 8);
  int* deg = (int*)ealloc((size_t)Nn * 4);
  int* cursor = (int*)ealloc((size_t)Nn * 4);
  int* bsum = (int*)ealloc(256 * 4);

  q = arena;  // late overlay
  float* u = (float*)ealloc((size_t)Nn * 128 * 4);
  unsigned short* ub = (unsigned short*)ealloc((size_t)Nn * 128 * 2);
  float* gate_u = (float*)ealloc((size_t)Nn * 128 * 4);

  hipMemsetAsync(deg, 0, (size_t)Nn * 4, stream);
  prep_weights<<<(768 * 128 + 255) / 256, 256, 0, stream>>>(Wq, bq, Wk, bk, Wv, bv, Ws, bs,
                                                            Wsp, bsp, Wg, bg, WcatT, WgTopT, bcat);
  prep_wefrag<<<16, 256, 0, stream>>>(We, wefrag);
  convert_bf16<<<((Nn * 128 / 4) + 255) / 256, 256, 0, stream>>>(x, xb, Nn * 128 / 4);
  convert_bf16<<<((E * 16 / 4) + 255) / 256, 256, 0, stream>>>(edge_attr, attrb, E * 16 / 4);
  count_deg<<<(E + 255) / 256, 256, 0, stream>>>(edge_index + E, deg, E);

  int G = (Nn + 1023) >> 10;
  scan_bsum<<<G, 256, 0, stream>>>(deg, bsum, Nn);
  scan_top<<<1, 64, 0, stream>>>(bsum, G);
  scan_write<<<G, 256, 0, stream>>>(deg, bsum, off, cursor, Nn);
  scatter_kernel<<<(E + 255) / 256, 256, 0, stream>>>(edge_index, cursor, slotsrc, E);

  gemm_fused<<<(Nn + 127) / 128, 256, 0, stream>>>(xb, WcatT, bcat, Y, Nn);

  edge_flash<<<(Nn + 1) / 2, 256, 0, stream>>>(slotsrc, off, attrb, wefrag, Y, agg, Nn);

  ln_gelu_kernel<<<(Nn + 3) / 4, 256, 0, stream>>>(agg, Y, g1, b1, u, ub, Nn);

  gemm_single<<<(Nn + 127) / 128, 256, 0, stream>>>(ub, WgTopT, gate_u, Nn);

  gate_ln_kernel<<<(Nn + 3) / 4, 256, 0, stream>>>(gate_u, Y, u, g2, b2, (float*)d_out, Nn);
}